// Round 4
// baseline (646.213 us; speedup 1.0000x reference)
//
#include <hip/hip_runtime.h>
#include <hip/hip_bf16.h>

typedef __hip_bfloat16 bf16;
typedef __attribute__((ext_vector_type(8))) short bf16x8;
typedef __attribute__((ext_vector_type(4))) float f32x4;

__device__ __forceinline__ void gload_lds16(const void* g, void* s) {
  __builtin_amdgcn_global_load_lds(
      (__attribute__((address_space(1))) void*)(unsigned long long)(uintptr_t)g,
      (__attribute__((address_space(3))) void*)(unsigned int)(uintptr_t)s,
      16, 0, 0);
}

__device__ __forceinline__ float gelu_new(float x) {
  float x3 = x * x * x;
  return 0.5f * x * (1.0f + tanhf(0.7978845608028654f * (x + 0.044715f * x3)));
}

__device__ __forceinline__ float bf16bits_to_f32(unsigned short u) {
  return __uint_as_float(((unsigned)u) << 16);
}

// ---------------------------------------------------------------- weight transpose+cast: W[K][N] f32 -> Wt[N][K] bf16
__global__ __launch_bounds__(256) void transpose_cvt(
    const float* __restrict__ W, bf16* __restrict__ Wt, int K, int N) {
  __shared__ float t[64][65];
  const int k0 = blockIdx.y << 6, n0 = blockIdx.x << 6;
  const int tid = threadIdx.x;
#pragma unroll
  for (int i = 0; i < 16; i++) {
    int idx = (i << 8) + tid;
    int r = idx >> 6, c = idx & 63;
    t[r][c] = W[(size_t)(k0 + r) * N + n0 + c];
  }
  __syncthreads();
#pragma unroll
  for (int i = 0; i < 16; i++) {
    int idx = (i << 8) + tid;
    int r = idx >> 6, c = idx & 63;
    Wt[(size_t)(n0 + r) * K + k0 + c] = __float2bfloat16(t[c][r]);
  }
}

// ---------------------------------------------------------------- layernorm, f32 input -> bf16 out (D=1024, block=256)
__global__ __launch_bounds__(256) void ln_f32in(
    const float* __restrict__ x, const float* __restrict__ g,
    const float* __restrict__ b, bf16* __restrict__ out) {
  const int row = blockIdx.x, tid = threadIdx.x;
  const float4 v = reinterpret_cast<const float4*>(x + (size_t)row * 1024)[tid];
  float s1 = v.x + v.y + v.z + v.w;
  float s2 = v.x * v.x + v.y * v.y + v.z * v.z + v.w * v.w;
#pragma unroll
  for (int off = 32; off >= 1; off >>= 1) {
    s1 += __shfl_xor(s1, off);
    s2 += __shfl_xor(s2, off);
  }
  __shared__ float red[8];
  const int wave = tid >> 6;
  if ((tid & 63) == 0) { red[wave * 2] = s1; red[wave * 2 + 1] = s2; }
  __syncthreads();
  s1 = red[0] + red[2] + red[4] + red[6];
  s2 = red[1] + red[3] + red[5] + red[7];
  const float mean = s1 * (1.0f / 1024.0f);
  const float var = s2 * (1.0f / 1024.0f) - mean * mean;
  const float inv = rsqrtf(var + 1e-5f);
  const float4 gv = reinterpret_cast<const float4*>(g)[tid];
  const float4 bv = reinterpret_cast<const float4*>(b)[tid];
  union { bf16 h[4]; uint2 u; } pk;
  pk.h[0] = __float2bfloat16((v.x - mean) * inv * gv.x + bv.x);
  pk.h[1] = __float2bfloat16((v.y - mean) * inv * gv.y + bv.y);
  pk.h[2] = __float2bfloat16((v.z - mean) * inv * gv.z + bv.z);
  pk.h[3] = __float2bfloat16((v.w - mean) * inv * gv.w + bv.w);
  reinterpret_cast<uint2*>(out + (size_t)row * 1024)[tid] = pk.u;
}

// ---------------------------------------------------------------- layernorm, bf16 input -> bf16 out
__global__ __launch_bounds__(256) void ln_bf16in(
    const bf16* __restrict__ x, const float* __restrict__ g,
    const float* __restrict__ b, bf16* __restrict__ out) {
  const int row = blockIdx.x, tid = threadIdx.x;
  union { uint2 u; unsigned short h[4]; } raw;
  raw.u = reinterpret_cast<const uint2*>(x + (size_t)row * 1024)[tid];
  float v[4];
#pragma unroll
  for (int j = 0; j < 4; j++) v[j] = bf16bits_to_f32(raw.h[j]);
  float s1 = v[0] + v[1] + v[2] + v[3];
  float s2 = v[0] * v[0] + v[1] * v[1] + v[2] * v[2] + v[3] * v[3];
#pragma unroll
  for (int off = 32; off >= 1; off >>= 1) {
    s1 += __shfl_xor(s1, off);
    s2 += __shfl_xor(s2, off);
  }
  __shared__ float red[8];
  const int wave = tid >> 6;
  if ((tid & 63) == 0) { red[wave * 2] = s1; red[wave * 2 + 1] = s2; }
  __syncthreads();
  s1 = red[0] + red[2] + red[4] + red[6];
  s2 = red[1] + red[3] + red[5] + red[7];
  const float mean = s1 * (1.0f / 1024.0f);
  const float var = s2 * (1.0f / 1024.0f) - mean * mean;
  const float inv = rsqrtf(var + 1e-5f);
  const float4 gv = reinterpret_cast<const float4*>(g)[tid];
  const float4 bv = reinterpret_cast<const float4*>(b)[tid];
  union { bf16 h[4]; uint2 u; } pk;
#pragma unroll
  for (int j = 0; j < 4; j++) {
    float gj = (&gv.x)[j], bj = (&bv.x)[j];
    pk.h[j] = __float2bfloat16((v[j] - mean) * inv * gj + bj);
  }
  reinterpret_cast<uint2*>(out + (size_t)row * 1024)[tid] = pk.u;
}

// ---------------------------------------------------------------- GEMM: C[M,N] = A[M,K](bf16) * Wt[N,K](bf16)^T + epilogue
// 128x128 tile, BK=64, 4 waves (2x2), each wave 64x64 = 4x4 frags of 16x16x32.
// EPI: 0 = +bias, scatter to qkv[3][B][H][S][HD] bf16
//      1 = +bias +resid(f32)  -> bf16
//      2 = +bias, gelu        -> bf16
//      3 = +bias +resid(bf16) -> f32   (final output, f32 dtype!)
template <int EPI>
__global__ __launch_bounds__(256) void gemm_bt(
    const bf16* __restrict__ A, const bf16* __restrict__ W,
    const float* __restrict__ bias, const void* __restrict__ resid,
    void* __restrict__ Cout, int N, int K) {
  __shared__ __align__(16) bf16 As[128 * 64];
  __shared__ __align__(16) bf16 Bs[128 * 64];
  const int tid = threadIdx.x;
  const int wave = tid >> 6, lane = tid & 63;
  const int row0 = blockIdx.y << 7, col0 = blockIdx.x << 7;
  const int wr = (wave >> 1) << 6, wc = (wave & 1) << 6;
  const bf16* Ag = A + (size_t)row0 * K;
  const bf16* Bg = W + (size_t)col0 * K;

  f32x4 acc[4][4];
#pragma unroll
  for (int m = 0; m < 4; m++)
#pragma unroll
    for (int n = 0; n < 4; n++) acc[m][n] = (f32x4){0.f, 0.f, 0.f, 0.f};

  const int lr = lane >> 3, lc = (lane & 7) << 3;
  auto stage = [&](int kt) {
    const bf16* ag = Ag + (kt << 6);
    const bf16* bg = Bg + (kt << 6);
#pragma unroll
    for (int i = 0; i < 4; i++) {
      int br = (i << 5) + (wave << 3);
      gload_lds16(ag + (size_t)(br + lr) * K + lc, As + br * 64);
      gload_lds16(bg + (size_t)(br + lr) * K + lc, Bs + br * 64);
    }
  };
  stage(0);
  const int nk = K >> 6;
  for (int kt = 0; kt < nk; kt++) {
    __syncthreads();  // drains vmcnt -> tile visible
#pragma unroll
    for (int kk = 0; kk < 2; kk++) {
      bf16x8 af[4], bfr[4];
      const int ko = (kk << 5) + ((lane >> 4) << 3);
#pragma unroll
      for (int m = 0; m < 4; m++)
        af[m] = *reinterpret_cast<const bf16x8*>(As + (wr + (m << 4) + (lane & 15)) * 64 + ko);
#pragma unroll
      for (int n = 0; n < 4; n++)
        bfr[n] = *reinterpret_cast<const bf16x8*>(Bs + (wc + (n << 4) + (lane & 15)) * 64 + ko);
#pragma unroll
      for (int m = 0; m < 4; m++)
#pragma unroll
        for (int n = 0; n < 4; n++)
          acc[m][n] = __builtin_amdgcn_mfma_f32_16x16x32_bf16(af[m], bfr[n], acc[m][n], 0, 0, 0);
    }
    __syncthreads();  // all reads done before restage
    if (kt + 1 < nk) stage(kt + 1);
  }
  // epilogue: C frag mapping col=lane&15, row=(lane>>4)*4+j  [m89-verified]
  const int rbase = row0 + wr + ((lane >> 4) << 2);
  const int cbase = col0 + wc + (lane & 15);
#pragma unroll
  for (int m = 0; m < 4; m++) {
#pragma unroll
    for (int n = 0; n < 4; n++) {
      const int col = cbase + (n << 4);
      const float bv = bias[col];
#pragma unroll
      for (int j = 0; j < 4; j++) {
        const int row = rbase + (m << 4) + j;
        float v = acc[m][n][j] + bv;
        if constexpr (EPI == 0) {
          int part = col >> 10, rem = col & 1023;
          int hh = rem >> 6, hd = rem & 63;
          int b = row >> 11, sq = row & 2047;
          ((bf16*)Cout)[(size_t)part * 8388608 +
                        ((size_t)((b << 4) + hh) * 2048 + sq) * 64 + hd] =
              __float2bfloat16(v);
        } else if constexpr (EPI == 1) {
          v += ((const float*)resid)[(size_t)row * N + col];
          ((bf16*)Cout)[(size_t)row * N + col] = __float2bfloat16(v);
        } else if constexpr (EPI == 2) {
          ((bf16*)Cout)[(size_t)row * N + col] = __float2bfloat16(gelu_new(v));
        } else {
          v += bf16bits_to_f32(((const unsigned short*)resid)[(size_t)row * N + col]);
          ((float*)Cout)[(size_t)row * N + col] = v;   // f32 OUTPUT
        }
      }
    }
  }
}

// ---------------------------------------------------------------- flash attention, causal, S=2048 HD=64
__global__ __launch_bounds__(256) void attn_k(
    const bf16* __restrict__ Qb, const bf16* __restrict__ Kb,
    const bf16* __restrict__ Vb, const float* __restrict__ amask,
    bf16* __restrict__ Aout) {
  __shared__ __align__(16) bf16 Ks[64 * 64];
  __shared__ __align__(16) bf16 Vt[64 * 64];   // transposed: [hd][kv]
  __shared__ __align__(16) bf16 Ps[128 * 64];
  const int tid = threadIdx.x, wave = tid >> 6, lane = tid & 63;
  const int qt = blockIdx.x, bh = blockIdx.y;
  const int b = bh >> 4, h = bh & 15;
  const size_t base = (size_t)bh * 2048 * 64;
  const int q0 = qt << 7;

  bf16x8 qf[2][2];
  const int qrow = q0 + (wave << 5) + (lane & 15);
#pragma unroll
  for (int m = 0; m < 2; m++)
#pragma unroll
    for (int kk = 0; kk < 2; kk++)
      qf[m][kk] = *reinterpret_cast<const bf16x8*>(
          Qb + base + (size_t)(qrow + (m << 4)) * 64 + (kk << 5) + ((lane >> 4) << 3));

  f32x4 oacc[2][4];
  float mst[2][4], lst[2][4];
#pragma unroll
  for (int m = 0; m < 2; m++) {
#pragma unroll
    for (int n = 0; n < 4; n++) oacc[m][n] = (f32x4){0.f, 0.f, 0.f, 0.f};
#pragma unroll
    for (int j = 0; j < 4; j++) { mst[m][j] = -INFINITY; lst[m][j] = 0.f; }
  }

  const int ktmax = (q0 + 127) >> 6;
  const bf16* Kg0 = Kb + base;
  const bf16* Vg0 = Vb + base;

  for (int kt = 0; kt <= ktmax; kt++) {
    const bf16* Kg = Kg0 + (kt << 12);
    const bf16* Vg = Vg0 + (kt << 12);
    bf16x8 rk[2], rv[2];
#pragma unroll
    for (int i = 0; i < 2; i++) {
      const int ci = (i << 8) + tid;
      const int r = ci >> 3, cb = (ci & 7) << 3;
      rk[i] = *reinterpret_cast<const bf16x8*>(Kg + r * 64 + cb);
      rv[i] = *reinterpret_cast<const bf16x8*>(Vg + r * 64 + cb);
    }
    __syncthreads();
#pragma unroll
    for (int i = 0; i < 2; i++) {
      const int ci = (i << 8) + tid;
      const int r = ci >> 3, cb = (ci & 7) << 3;
      *reinterpret_cast<bf16x8*>(Ks + r * 64 + cb) = rk[i];
      short* VtS = reinterpret_cast<short*>(Vt);
#pragma unroll
      for (int j = 0; j < 8; j++) VtS[(cb + j) * 64 + r] = rv[i][j];
    }
    __syncthreads();

    f32x4 s[2][4];
#pragma unroll
    for (int m = 0; m < 2; m++)
#pragma unroll
      for (int n = 0; n < 4; n++) s[m][n] = (f32x4){0.f, 0.f, 0.f, 0.f};
#pragma unroll
    for (int kk = 0; kk < 2; kk++) {
      bf16x8 kf[4];
      const int ko = (kk << 5) + ((lane >> 4) << 3);
#pragma unroll
      for (int n = 0; n < 4; n++)
        kf[n] = *reinterpret_cast<const bf16x8*>(Ks + ((n << 4) + (lane & 15)) * 64 + ko);
#pragma unroll
      for (int m = 0; m < 2; m++)
#pragma unroll
        for (int n = 0; n < 4; n++)
          s[m][n] = __builtin_amdgcn_mfma_f32_16x16x32_bf16(qf[m][kk], kf[n], s[m][n], 0, 0, 0);
    }
    float am[4];
#pragma unroll
    for (int n = 0; n < 4; n++)
      am[n] = amask[b * 2048 + (kt << 6) + (n << 4) + (lane & 15)];
    const int rq = q0 + (wave << 5) + ((lane >> 4) << 2);
#pragma unroll
    for (int m = 0; m < 2; m++)
#pragma unroll
      for (int n = 0; n < 4; n++)
#pragma unroll
        for (int j = 0; j < 4; j++) {
          int r = rq + (m << 4) + j;
          int c = (kt << 6) + (n << 4) + (lane & 15);
          float v = s[m][n][j] * 0.125f + am[n];
          if (c > r) v = -1e30f;
          s[m][n][j] = v;
        }
#pragma unroll
    for (int m = 0; m < 2; m++) {
#pragma unroll
      for (int j = 0; j < 4; j++) {
        float rm = -INFINITY;
#pragma unroll
        for (int n = 0; n < 4; n++) rm = fmaxf(rm, s[m][n][j]);
#pragma unroll
        for (int off = 1; off < 16; off <<= 1) rm = fmaxf(rm, __shfl_xor(rm, off));
        float mnew = fmaxf(mst[m][j], rm);
        float fac = __expf(mst[m][j] - mnew);
        float rs = 0.f;
#pragma unroll
        for (int n = 0; n < 4; n++) {
          float p = __expf(s[m][n][j] - mnew);
          s[m][n][j] = p;
          rs += p;
        }
#pragma unroll
        for (int off = 1; off < 16; off <<= 1) rs += __shfl_xor(rs, off);
        lst[m][j] = lst[m][j] * fac + rs;
        mst[m][j] = mnew;
#pragma unroll
        for (int n = 0; n < 4; n++) oacc[m][n][j] *= fac;
      }
    }
#pragma unroll
    for (int m = 0; m < 2; m++)
#pragma unroll
      for (int n = 0; n < 4; n++)
#pragma unroll
        for (int j = 0; j < 4; j++)
          Ps[((wave << 5) + (m << 4) + ((lane >> 4) << 2) + j) * 64 + (n << 4) + (lane & 15)] =
              __float2bfloat16(s[m][n][j]);
    __syncthreads();
#pragma unroll
    for (int kk = 0; kk < 2; kk++) {
      bf16x8 pa[2], vb[4];
      const int ko = (kk << 5) + ((lane >> 4) << 3);
#pragma unroll
      for (int m = 0; m < 2; m++)
        pa[m] = *reinterpret_cast<const bf16x8*>(Ps + ((wave << 5) + (m << 4) + (lane & 15)) * 64 + ko);
#pragma unroll
      for (int n = 0; n < 4; n++)
        vb[n] = *reinterpret_cast<const bf16x8*>(Vt + ((n << 4) + (lane & 15)) * 64 + ko);
#pragma unroll
      for (int m = 0; m < 2; m++)
#pragma unroll
        for (int n = 0; n < 4; n++)
          oacc[m][n] = __builtin_amdgcn_mfma_f32_16x16x32_bf16(pa[m], vb[n], oacc[m][n], 0, 0, 0);
    }
  }
#pragma unroll
  for (int m = 0; m < 2; m++)
#pragma unroll
    for (int n = 0; n < 4; n++)
#pragma unroll
      for (int j = 0; j < 4; j++) {
        int r = q0 + (wave << 5) + (m << 4) + ((lane >> 4) << 2) + j;
        int c = (h << 6) + (n << 4) + (lane & 15);
        float v = oacc[m][n][j] / lst[m][j];
        Aout[((size_t)(b * 2048 + r)) * 1024 + c] = __float2bfloat16(v);
      }
}

// ---------------------------------------------------------------- launch
extern "C" void kernel_launch(void* const* d_in, const int* in_sizes, int n_in,
                              void* d_out, int out_size, void* d_ws, size_t ws_size,
                              hipStream_t stream) {
  const float* hid   = (const float*)d_in[0];
  const float* amask = (const float*)d_in[1];
  const float* ln1g  = (const float*)d_in[2];
  const float* ln1b  = (const float*)d_in[3];
  const float* Wa    = (const float*)d_in[4];
  const float* ba    = (const float*)d_in[5];
  const float* Wp    = (const float*)d_in[6];
  const float* bp    = (const float*)d_in[7];
  const float* ln2g  = (const float*)d_in[8];
  const float* ln2b  = (const float*)d_in[9];
  const float* Wf    = (const float*)d_in[10];
  const float* bfc   = (const float*)d_in[11];
  const float* Wf2   = (const float*)d_in[12];
  const float* bf2   = (const float*)d_in[13];
  float* out = (float*)d_out;   // reference output dtype is FLOAT32

  if (ws_size < 125829120u) return;  // 120 MB layout (proven to fit in round 2)
  char* ws = (char*)d_ws;
  bf16* WtA  = (bf16*)(ws + 0);          //  6 MB
  bf16* WtP  = (bf16*)(ws + 6291456);    //  2 MB
  bf16* WtF  = (bf16*)(ws + 8388608);    //  8 MB
  bf16* WtF2 = (bf16*)(ws + 16777216);   //  8 MB
  bf16* h    = (bf16*)(ws + 25165824);   // 16 MB (reused as h2)
  bf16* qkv  = (bf16*)(ws + 41943040);   // 48 MB
  bf16* a    = (bf16*)(ws + 92274688);   // 16 MB
  bf16* xmid = (bf16*)(ws + 109051904);  // 16 MB -> total 120 MB
  bf16* h2  = h;
  bf16* fc1 = qkv;  // overlays qkv+a (both dead): 64 MB

  dim3 blk(256);
  transpose_cvt<<<dim3(48, 16), blk, 0, stream>>>(Wa, WtA, 1024, 3072);
  transpose_cvt<<<dim3(16, 16), blk, 0, stream>>>(Wp, WtP, 1024, 1024);
  transpose_cvt<<<dim3(64, 16), blk, 0, stream>>>(Wf, WtF, 1024, 4096);
  transpose_cvt<<<dim3(16, 64), blk, 0, stream>>>(Wf2, WtF2, 4096, 1024);

  ln_f32in<<<8192, blk, 0, stream>>>(hid, ln1g, ln1b, h);
  gemm_bt<0><<<dim3(24, 64), blk, 0, stream>>>(h, WtA, ba, nullptr, qkv, 3072, 1024);
  attn_k<<<dim3(16, 64), blk, 0, stream>>>(qkv, qkv + 8388608, qkv + 16777216, amask, a);
  gemm_bt<1><<<dim3(8, 64), blk, 0, stream>>>(a, WtP, bp, hid, xmid, 1024, 1024);
  ln_bf16in<<<8192, blk, 0, stream>>>(xmid, ln2g, ln2b, h2);
  gemm_bt<2><<<dim3(32, 64), blk, 0, stream>>>(h2, WtF, bfc, nullptr, fc1, 4096, 1024);
  gemm_bt<3><<<dim3(8, 64), blk, 0, stream>>>(fc1, WtF2, bf2, xmid, out, 1024, 4096);
}

// Round 6
// 516.038 us; speedup vs baseline: 1.2523x; 1.2523x over previous
//
#include <hip/hip_runtime.h>
#include <hip/hip_bf16.h>

typedef __hip_bfloat16 bf16;
typedef __attribute__((ext_vector_type(8))) short bf16x8;
typedef __attribute__((ext_vector_type(4))) float f32x4;

__device__ __forceinline__ void gload_lds16(const void* g, void* s) {
  __builtin_amdgcn_global_load_lds(
      (__attribute__((address_space(1))) void*)(unsigned long long)(uintptr_t)g,
      (__attribute__((address_space(3))) void*)(unsigned int)(uintptr_t)s,
      16, 0, 0);
}

__device__ __forceinline__ float gelu_new(float x) {
  float x3 = x * x * x;
  return 0.5f * x * (1.0f + tanhf(0.7978845608028654f * (x + 0.044715f * x3)));
}

__device__ __forceinline__ float bf16bits_to_f32(unsigned short u) {
  return __uint_as_float(((unsigned)u) << 16);
}

// ---------------------------------------------------------------- weight transpose+cast: W[K][N] f32 -> Wt[N][K] bf16
__global__ __launch_bounds__(256) void transpose_cvt(
    const float* __restrict__ W, bf16* __restrict__ Wt, int K, int N) {
  __shared__ float t[64][65];
  const int k0 = blockIdx.y << 6, n0 = blockIdx.x << 6;
  const int tid = threadIdx.x;
#pragma unroll
  for (int i = 0; i < 16; i++) {
    int idx = (i << 8) + tid;
    int r = idx >> 6, c = idx & 63;
    t[r][c] = W[(size_t)(k0 + r) * N + n0 + c];
  }
  __syncthreads();
#pragma unroll
  for (int i = 0; i < 16; i++) {
    int idx = (i << 8) + tid;
    int r = idx >> 6, c = idx & 63;
    Wt[(size_t)(n0 + r) * K + k0 + c] = __float2bfloat16(t[c][r]);
  }
}

// ---------------------------------------------------------------- layernorm, f32 input -> bf16 out (D=1024, block=256)
__global__ __launch_bounds__(256) void ln_f32in(
    const float* __restrict__ x, const float* __restrict__ g,
    const float* __restrict__ b, bf16* __restrict__ out) {
  const int row = blockIdx.x, tid = threadIdx.x;
  const float4 v = reinterpret_cast<const float4*>(x + (size_t)row * 1024)[tid];
  float s1 = v.x + v.y + v.z + v.w;
  float s2 = v.x * v.x + v.y * v.y + v.z * v.z + v.w * v.w;
#pragma unroll
  for (int off = 32; off >= 1; off >>= 1) {
    s1 += __shfl_xor(s1, off);
    s2 += __shfl_xor(s2, off);
  }
  __shared__ float red[8];
  const int wave = tid >> 6;
  if ((tid & 63) == 0) { red[wave * 2] = s1; red[wave * 2 + 1] = s2; }
  __syncthreads();
  s1 = red[0] + red[2] + red[4] + red[6];
  s2 = red[1] + red[3] + red[5] + red[7];
  const float mean = s1 * (1.0f / 1024.0f);
  const float var = s2 * (1.0f / 1024.0f) - mean * mean;
  const float inv = rsqrtf(var + 1e-5f);
  const float4 gv = reinterpret_cast<const float4*>(g)[tid];
  const float4 bv = reinterpret_cast<const float4*>(b)[tid];
  union { bf16 h[4]; uint2 u; } pk;
  pk.h[0] = __float2bfloat16((v.x - mean) * inv * gv.x + bv.x);
  pk.h[1] = __float2bfloat16((v.y - mean) * inv * gv.y + bv.y);
  pk.h[2] = __float2bfloat16((v.z - mean) * inv * gv.z + bv.z);
  pk.h[3] = __float2bfloat16((v.w - mean) * inv * gv.w + bv.w);
  reinterpret_cast<uint2*>(out + (size_t)row * 1024)[tid] = pk.u;
}

// ---------------------------------------------------------------- layernorm, bf16 input -> bf16 out
__global__ __launch_bounds__(256) void ln_bf16in(
    const bf16* __restrict__ x, const float* __restrict__ g,
    const float* __restrict__ b, bf16* __restrict__ out) {
  const int row = blockIdx.x, tid = threadIdx.x;
  union { uint2 u; unsigned short h[4]; } raw;
  raw.u = reinterpret_cast<const uint2*>(x + (size_t)row * 1024)[tid];
  float v[4];
#pragma unroll
  for (int j = 0; j < 4; j++) v[j] = bf16bits_to_f32(raw.h[j]);
  float s1 = v[0] + v[1] + v[2] + v[3];
  float s2 = v[0] * v[0] + v[1] * v[1] + v[2] * v[2] + v[3] * v[3];
#pragma unroll
  for (int off = 32; off >= 1; off >>= 1) {
    s1 += __shfl_xor(s1, off);
    s2 += __shfl_xor(s2, off);
  }
  __shared__ float red[8];
  const int wave = tid >> 6;
  if ((tid & 63) == 0) { red[wave * 2] = s1; red[wave * 2 + 1] = s2; }
  __syncthreads();
  s1 = red[0] + red[2] + red[4] + red[6];
  s2 = red[1] + red[3] + red[5] + red[7];
  const float mean = s1 * (1.0f / 1024.0f);
  const float var = s2 * (1.0f / 1024.0f) - mean * mean;
  const float inv = rsqrtf(var + 1e-5f);
  const float4 gv = reinterpret_cast<const float4*>(g)[tid];
  const float4 bv = reinterpret_cast<const float4*>(b)[tid];
  union { bf16 h[4]; uint2 u; } pk;
#pragma unroll
  for (int j = 0; j < 4; j++) {
    float gj = (&gv.x)[j], bj = (&bv.x)[j];
    pk.h[j] = __float2bfloat16((v[j] - mean) * inv * gj + bj);
  }
  reinterpret_cast<uint2*>(out + (size_t)row * 1024)[tid] = pk.u;
}

// ---------------------------------------------------------------- GEMM: C[M,N] = A[M,K](bf16) * Wt[N,K](bf16)^T + epilogue
template <int EPI>
__global__ __launch_bounds__(256) void gemm_bt(
    const bf16* __restrict__ A, const bf16* __restrict__ W,
    const float* __restrict__ bias, const void* __restrict__ resid,
    void* __restrict__ Cout, int N, int K) {
  __shared__ __align__(16) bf16 As[128 * 64];
  __shared__ __align__(16) bf16 Bs[128 * 64];
  const int tid = threadIdx.x;
  const int wave = tid >> 6, lane = tid & 63;
  const int row0 = blockIdx.y << 7, col0 = blockIdx.x << 7;
  const int wr = (wave >> 1) << 6, wc = (wave & 1) << 6;
  const bf16* Ag = A + (size_t)row0 * K;
  const bf16* Bg = W + (size_t)col0 * K;

  f32x4 acc[4][4];
#pragma unroll
  for (int m = 0; m < 4; m++)
#pragma unroll
    for (int n = 0; n < 4; n++) acc[m][n] = (f32x4){0.f, 0.f, 0.f, 0.f};

  const int lr = lane >> 3, lc = (lane & 7) << 3;
  auto stage = [&](int kt) {
    const bf16* ag = Ag + (kt << 6);
    const bf16* bg = Bg + (kt << 6);
#pragma unroll
    for (int i = 0; i < 4; i++) {
      int br = (i << 5) + (wave << 3);
      gload_lds16(ag + (size_t)(br + lr) * K + lc, As + br * 64);
      gload_lds16(bg + (size_t)(br + lr) * K + lc, Bs + br * 64);
    }
  };
  stage(0);
  const int nk = K >> 6;
  for (int kt = 0; kt < nk; kt++) {
    __syncthreads();
#pragma unroll
    for (int kk = 0; kk < 2; kk++) {
      bf16x8 af[4], bfr[4];
      const int ko = (kk << 5) + ((lane >> 4) << 3);
#pragma unroll
      for (int m = 0; m < 4; m++)
        af[m] = *reinterpret_cast<const bf16x8*>(As + (wr + (m << 4) + (lane & 15)) * 64 + ko);
#pragma unroll
      for (int n = 0; n < 4; n++)
        bfr[n] = *reinterpret_cast<const bf16x8*>(Bs + (wc + (n << 4) + (lane & 15)) * 64 + ko);
#pragma unroll
      for (int m = 0; m < 4; m++)
#pragma unroll
        for (int n = 0; n < 4; n++)
          acc[m][n] = __builtin_amdgcn_mfma_f32_16x16x32_bf16(af[m], bfr[n], acc[m][n], 0, 0, 0);
    }
    __syncthreads();
    if (kt + 1 < nk) stage(kt + 1);
  }
  const int rbase = row0 + wr + ((lane >> 4) << 2);
  const int cbase = col0 + wc + (lane & 15);
#pragma unroll
  for (int m = 0; m < 4; m++) {
#pragma unroll
    for (int n = 0; n < 4; n++) {
      const int col = cbase + (n << 4);
      const float bv = bias[col];
#pragma unroll
      for (int j = 0; j < 4; j++) {
        const int row = rbase + (m << 4) + j;
        float v = acc[m][n][j] + bv;
        if constexpr (EPI == 0) {
          int part = col >> 10, rem = col & 1023;
          int hh = rem >> 6, hd = rem & 63;
          int b = row >> 11, sq = row & 2047;
          ((bf16*)Cout)[(size_t)part * 8388608 +
                        ((size_t)((b << 4) + hh) * 2048 + sq) * 64 + hd] =
              __float2bfloat16(v);
        } else if constexpr (EPI == 1) {
          v += ((const float*)resid)[(size_t)row * N + col];
          ((bf16*)Cout)[(size_t)row * N + col] = __float2bfloat16(v);
        } else if constexpr (EPI == 2) {
          ((bf16*)Cout)[(size_t)row * N + col] = __float2bfloat16(gelu_new(v));
        } else {
          v += bf16bits_to_f32(((const unsigned short*)resid)[(size_t)row * N + col]);
          ((float*)Cout)[(size_t)row * N + col] = v;
        }
      }
    }
  }
}

// ---------------------------------------------------------------- flash attention, causal, S=2048 HD=64
// ROUND-4 internals (passing) + load-balance pairing: grid (8, 64); block p does
// q-tiles {p, 15-p} (128 rows each) -> uniform 36 kt-iters per block.
// Ps stride padded 64 -> 72 (kills 16-way bank conflict on P write/read).
__global__ __launch_bounds__(256) void attn_k(
    const bf16* __restrict__ Qb, const bf16* __restrict__ Kb,
    const bf16* __restrict__ Vb, const float* __restrict__ amask,
    bf16* __restrict__ Aout) {
  __shared__ __align__(16) bf16 Ks[64 * 64];
  __shared__ __align__(16) bf16 Vt[64 * 64];   // transposed: [hd][kv]
  __shared__ __align__(16) bf16 Ps[128][72];   // P, padded stride (144B)
  const int tid = threadIdx.x, wave = tid >> 6, lane = tid & 63;
  const int p = blockIdx.x, bh = blockIdx.y;
  const int b = bh >> 4, h = bh & 15;
  const size_t base = (size_t)bh * 131072;
  const bf16* Kg0 = Kb + base;
  const bf16* Vg0 = Vb + base;

  for (int ph = 0; ph < 2; ph++) {
    const int qt = ph ? (15 - p) : p;
    const int q0 = qt << 7;

    bf16x8 qf[2][2];
    const int qrow = q0 + (wave << 5) + (lane & 15);
#pragma unroll
    for (int m = 0; m < 2; m++)
#pragma unroll
      for (int kk = 0; kk < 2; kk++)
        qf[m][kk] = *reinterpret_cast<const bf16x8*>(
            Qb + base + (size_t)(qrow + (m << 4)) * 64 + (kk << 5) + ((lane >> 4) << 3));

    f32x4 oacc[2][4];
    float mst[2][4], lst[2][4];
#pragma unroll
    for (int m = 0; m < 2; m++) {
#pragma unroll
      for (int n = 0; n < 4; n++) oacc[m][n] = (f32x4){0.f, 0.f, 0.f, 0.f};
#pragma unroll
      for (int j = 0; j < 4; j++) { mst[m][j] = -INFINITY; lst[m][j] = 0.f; }
    }

    const int ktmax = (q0 + 127) >> 6;  // inclusive
    for (int kt = 0; kt <= ktmax; kt++) {
      const bf16* Kg = Kg0 + (kt << 12);
      const bf16* Vg = Vg0 + (kt << 12);
      bf16x8 rk[2], rv[2];
#pragma unroll
      for (int i = 0; i < 2; i++) {
        const int ci = (i << 8) + tid;
        const int r = ci >> 3, cb = (ci & 7) << 3;
        rk[i] = *reinterpret_cast<const bf16x8*>(Kg + r * 64 + cb);
        rv[i] = *reinterpret_cast<const bf16x8*>(Vg + r * 64 + cb);
      }
      __syncthreads();  // prev iter/phase reads of Ks/Vt done
#pragma unroll
      for (int i = 0; i < 2; i++) {
        const int ci = (i << 8) + tid;
        const int r = ci >> 3, cb = (ci & 7) << 3;
        *reinterpret_cast<bf16x8*>(Ks + r * 64 + cb) = rk[i];
        short* VtS = reinterpret_cast<short*>(Vt);
#pragma unroll
        for (int j = 0; j < 8; j++) VtS[(cb + j) * 64 + r] = rv[i][j];
      }
      __syncthreads();

      f32x4 s[2][4];
#pragma unroll
      for (int m = 0; m < 2; m++)
#pragma unroll
        for (int n = 0; n < 4; n++) s[m][n] = (f32x4){0.f, 0.f, 0.f, 0.f};
#pragma unroll
      for (int kk = 0; kk < 2; kk++) {
        bf16x8 kf[4];
        const int ko = (kk << 5) + ((lane >> 4) << 3);
#pragma unroll
        for (int n = 0; n < 4; n++)
          kf[n] = *reinterpret_cast<const bf16x8*>(Ks + ((n << 4) + (lane & 15)) * 64 + ko);
#pragma unroll
        for (int m = 0; m < 2; m++)
#pragma unroll
          for (int n = 0; n < 4; n++)
            s[m][n] = __builtin_amdgcn_mfma_f32_16x16x32_bf16(qf[m][kk], kf[n], s[m][n], 0, 0, 0);
      }
      float am[4];
#pragma unroll
      for (int n = 0; n < 4; n++)
        am[n] = amask[b * 2048 + (kt << 6) + (n << 4) + (lane & 15)];
      const int rq = q0 + (wave << 5) + ((lane >> 4) << 2);
#pragma unroll
      for (int m = 0; m < 2; m++)
#pragma unroll
        for (int n = 0; n < 4; n++)
#pragma unroll
          for (int j = 0; j < 4; j++) {
            int r = rq + (m << 4) + j;
            int c = (kt << 6) + (n << 4) + (lane & 15);
            float v = s[m][n][j] * 0.125f + am[n];
            if (c > r) v = -1e30f;
            s[m][n][j] = v;
          }
#pragma unroll
      for (int m = 0; m < 2; m++) {
#pragma unroll
        for (int j = 0; j < 4; j++) {
          float rm = -INFINITY;
#pragma unroll
          for (int n = 0; n < 4; n++) rm = fmaxf(rm, s[m][n][j]);
#pragma unroll
          for (int off = 1; off < 16; off <<= 1) rm = fmaxf(rm, __shfl_xor(rm, off));
          float mnew = fmaxf(mst[m][j], rm);
          float fac = __expf(mst[m][j] - mnew);
          float rs = 0.f;
#pragma unroll
          for (int n = 0; n < 4; n++) {
            float pv = __expf(s[m][n][j] - mnew);
            s[m][n][j] = pv;
            rs += pv;
          }
#pragma unroll
          for (int off = 1; off < 16; off <<= 1) rs += __shfl_xor(rs, off);
          lst[m][j] = lst[m][j] * fac + rs;
          mst[m][j] = mnew;
#pragma unroll
          for (int n = 0; n < 4; n++) oacc[m][n][j] *= fac;
        }
      }
#pragma unroll
      for (int m = 0; m < 2; m++)
#pragma unroll
        for (int n = 0; n < 4; n++)
#pragma unroll
          for (int j = 0; j < 4; j++)
            Ps[(wave << 5) + (m << 4) + ((lane >> 4) << 2) + j][(n << 4) + (lane & 15)] =
                __float2bfloat16(s[m][n][j]);
      __syncthreads();
#pragma unroll
      for (int kk = 0; kk < 2; kk++) {
        bf16x8 pa[2], vb[4];
        const int ko = (kk << 5) + ((lane >> 4) << 3);
#pragma unroll
        for (int m = 0; m < 2; m++)
          pa[m] = *reinterpret_cast<const bf16x8*>(&Ps[(wave << 5) + (m << 4) + (lane & 15)][ko]);
#pragma unroll
        for (int n = 0; n < 4; n++)
          vb[n] = *reinterpret_cast<const bf16x8*>(Vt + ((n << 4) + (lane & 15)) * 64 + ko);
#pragma unroll
        for (int m = 0; m < 2; m++)
#pragma unroll
          for (int n = 0; n < 4; n++)
            oacc[m][n] = __builtin_amdgcn_mfma_f32_16x16x32_bf16(pa[m], vb[n], oacc[m][n], 0, 0, 0);
      }
    }
#pragma unroll
    for (int m = 0; m < 2; m++)
#pragma unroll
      for (int n = 0; n < 4; n++)
#pragma unroll
        for (int j = 0; j < 4; j++) {
          int r = q0 + (wave << 5) + (m << 4) + ((lane >> 4) << 2) + j;
          int c = (h << 6) + (n << 4) + (lane & 15);
          float v = oacc[m][n][j] / lst[m][j];
          Aout[((size_t)(b * 2048 + r)) * 1024 + c] = __float2bfloat16(v);
        }
  }
}

// ---------------------------------------------------------------- launch
extern "C" void kernel_launch(void* const* d_in, const int* in_sizes, int n_in,
                              void* d_out, int out_size, void* d_ws, size_t ws_size,
                              hipStream_t stream) {
  const float* hid   = (const float*)d_in[0];
  const float* amask = (const float*)d_in[1];
  const float* ln1g  = (const float*)d_in[2];
  const float* ln1b  = (const float*)d_in[3];
  const float* Wa    = (const float*)d_in[4];
  const float* ba    = (const float*)d_in[5];
  const float* Wp    = (const float*)d_in[6];
  const float* bp    = (const float*)d_in[7];
  const float* ln2g  = (const float*)d_in[8];
  const float* ln2b  = (const float*)d_in[9];
  const float* Wf    = (const float*)d_in[10];
  const float* bfc   = (const float*)d_in[11];
  const float* Wf2   = (const float*)d_in[12];
  const float* bf2   = (const float*)d_in[13];
  float* out = (float*)d_out;   // reference output dtype is FLOAT32

  if (ws_size < 125829120u) return;  // 120 MB layout (proven to fit)
  char* ws = (char*)d_ws;
  bf16* WtA  = (bf16*)(ws + 0);          //  6 MB
  bf16* WtP  = (bf16*)(ws + 6291456);    //  2 MB
  bf16* WtF  = (bf16*)(ws + 8388608);    //  8 MB
  bf16* WtF2 = (bf16*)(ws + 16777216);   //  8 MB
  bf16* h    = (bf16*)(ws + 25165824);   // 16 MB (reused as h2)
  bf16* qkv  = (bf16*)(ws + 41943040);   // 48 MB
  bf16* a    = (bf16*)(ws + 92274688);   // 16 MB
  bf16* xmid = (bf16*)(ws + 109051904);  // 16 MB -> total 120 MB
  bf16* h2  = h;
  bf16* fc1 = qkv;  // overlays qkv+a (both dead): 64 MB

  dim3 blk(256);
  transpose_cvt<<<dim3(48, 16), blk, 0, stream>>>(Wa, WtA, 1024, 3072);
  transpose_cvt<<<dim3(16, 16), blk, 0, stream>>>(Wp, WtP, 1024, 1024);
  transpose_cvt<<<dim3(64, 16), blk, 0, stream>>>(Wf, WtF, 1024, 4096);
  transpose_cvt<<<dim3(16, 64), blk, 0, stream>>>(Wf2, WtF2, 4096, 1024);

  ln_f32in<<<8192, blk, 0, stream>>>(hid, ln1g, ln1b, h);
  gemm_bt<0><<<dim3(24, 64), blk, 0, stream>>>(h, WtA, ba, nullptr, qkv, 3072, 1024);
  attn_k<<<dim3(8, 64), blk, 0, stream>>>(qkv, qkv + 8388608, qkv + 16777216, amask, a);
  gemm_bt<1><<<dim3(8, 64), blk, 0, stream>>>(a, WtP, bp, hid, xmid, 1024, 1024);
  ln_bf16in<<<8192, blk, 0, stream>>>(xmid, ln2g, ln2b, h2);
  gemm_bt<2><<<dim3(32, 64), blk, 0, stream>>>(h2, WtF, bfc, nullptr, fc1, 4096, 1024);
  gemm_bt<3><<<dim3(8, 64), blk, 0, stream>>>(fc1, WtF2, bf2, xmid, out, 1024, 4096);
}

// Round 8
// 512.055 us; speedup vs baseline: 1.2620x; 1.0078x over previous
//
#include <hip/hip_runtime.h>
#include <hip/hip_bf16.h>

typedef __hip_bfloat16 bf16;
typedef __attribute__((ext_vector_type(8))) short bf16x8;
typedef __attribute__((ext_vector_type(4))) float f32x4;

__device__ __forceinline__ void gload_lds16(const void* g, void* s) {
  __builtin_amdgcn_global_load_lds(
      (__attribute__((address_space(1))) void*)(unsigned long long)(uintptr_t)g,
      (__attribute__((address_space(3))) void*)(unsigned int)(uintptr_t)s,
      16, 0, 0);
}

__device__ __forceinline__ float gelu_new(float x) {
  float x3 = x * x * x;
  return 0.5f * x * (1.0f + tanhf(0.7978845608028654f * (x + 0.044715f * x3)));
}

__device__ __forceinline__ float bf16bits_to_f32(unsigned short u) {
  return __uint_as_float(((unsigned)u) << 16);
}

// ---------------------------------------------------------------- weight transpose+cast: W[K][N] f32 -> Wt[N][K] bf16
__global__ __launch_bounds__(256) void transpose_cvt(
    const float* __restrict__ W, bf16* __restrict__ Wt, int K, int N) {
  __shared__ float t[64][65];
  const int k0 = blockIdx.y << 6, n0 = blockIdx.x << 6;
  const int tid = threadIdx.x;
#pragma unroll
  for (int i = 0; i < 16; i++) {
    int idx = (i << 8) + tid;
    int r = idx >> 6, c = idx & 63;
    t[r][c] = W[(size_t)(k0 + r) * N + n0 + c];
  }
  __syncthreads();
#pragma unroll
  for (int i = 0; i < 16; i++) {
    int idx = (i << 8) + tid;
    int r = idx >> 6, c = idx & 63;
    Wt[(size_t)(n0 + r) * K + k0 + c] = __float2bfloat16(t[c][r]);
  }
}

// ---------------------------------------------------------------- V transpose: V[bh][s][64] -> Vt[bh][64][s]  (bit-exact)
// FIXED vs rounds 5/7: LDS tile is raw `short` (bit copy, no bf16->int
// numeric conversion) and 16B-aligned for the b128 vector writes.
__global__ __launch_bounds__(256) void vt_k(
    const bf16* __restrict__ V, bf16* __restrict__ Vt) {
  __shared__ __align__(16) short t[64][72];
  const int tid = threadIdx.x;
  const int st = blockIdx.x, bh = blockIdx.y;
  const short* src = (const short*)(V + (size_t)bh * 131072 + (size_t)st * 4096);
#pragma unroll
  for (int i = 0; i < 2; i++) {
    int idx = (i << 8) + tid;
    int r = idx >> 3, c0 = (idx & 7) << 3;
    *reinterpret_cast<bf16x8*>(&t[r][c0]) =
        *reinterpret_cast<const bf16x8*>(src + r * 64 + c0);
  }
  __syncthreads();
  short* dst = (short*)(Vt + (size_t)bh * 131072 + (size_t)st * 64);
#pragma unroll
  for (int i = 0; i < 2; i++) {
    int idx = (i << 8) + tid;
    int hd = idx >> 3, s0 = (idx & 7) << 3;
    bf16x8 o;
#pragma unroll
    for (int j = 0; j < 8; j++) o[j] = t[s0 + j][hd];  // short = short: bit copy
    *reinterpret_cast<bf16x8*>(dst + (size_t)hd * 2048 + s0) = o;
  }
}

// ---------------------------------------------------------------- layernorm, f32 input -> bf16 out (D=1024, block=256)
__global__ __launch_bounds__(256) void ln_f32in(
    const float* __restrict__ x, const float* __restrict__ g,
    const float* __restrict__ b, bf16* __restrict__ out) {
  const int row = blockIdx.x, tid = threadIdx.x;
  const float4 v = reinterpret_cast<const float4*>(x + (size_t)row * 1024)[tid];
  float s1 = v.x + v.y + v.z + v.w;
  float s2 = v.x * v.x + v.y * v.y + v.z * v.z + v.w * v.w;
#pragma unroll
  for (int off = 32; off >= 1; off >>= 1) {
    s1 += __shfl_xor(s1, off);
    s2 += __shfl_xor(s2, off);
  }
  __shared__ float red[8];
  const int wave = tid >> 6;
  if ((tid & 63) == 0) { red[wave * 2] = s1; red[wave * 2 + 1] = s2; }
  __syncthreads();
  s1 = red[0] + red[2] + red[4] + red[6];
  s2 = red[1] + red[3] + red[5] + red[7];
  const float mean = s1 * (1.0f / 1024.0f);
  const float var = s2 * (1.0f / 1024.0f) - mean * mean;
  const float inv = rsqrtf(var + 1e-5f);
  const float4 gv = reinterpret_cast<const float4*>(g)[tid];
  const float4 bv = reinterpret_cast<const float4*>(b)[tid];
  union { bf16 h[4]; uint2 u; } pk;
  pk.h[0] = __float2bfloat16((v.x - mean) * inv * gv.x + bv.x);
  pk.h[1] = __float2bfloat16((v.y - mean) * inv * gv.y + bv.y);
  pk.h[2] = __float2bfloat16((v.z - mean) * inv * gv.z + bv.z);
  pk.h[3] = __float2bfloat16((v.w - mean) * inv * gv.w + bv.w);
  reinterpret_cast<uint2*>(out + (size_t)row * 1024)[tid] = pk.u;
}

// ---------------------------------------------------------------- layernorm, bf16 input -> bf16 out
__global__ __launch_bounds__(256) void ln_bf16in(
    const bf16* __restrict__ x, const float* __restrict__ g,
    const float* __restrict__ b, bf16* __restrict__ out) {
  const int row = blockIdx.x, tid = threadIdx.x;
  union { uint2 u; unsigned short h[4]; } raw;
  raw.u = reinterpret_cast<const uint2*>(x + (size_t)row * 1024)[tid];
  float v[4];
#pragma unroll
  for (int j = 0; j < 4; j++) v[j] = bf16bits_to_f32(raw.h[j]);
  float s1 = v[0] + v[1] + v[2] + v[3];
  float s2 = v[0] * v[0] + v[1] * v[1] + v[2] * v[2] + v[3] * v[3];
#pragma unroll
  for (int off = 32; off >= 1; off >>= 1) {
    s1 += __shfl_xor(s1, off);
    s2 += __shfl_xor(s2, off);
  }
  __shared__ float red[8];
  const int wave = tid >> 6;
  if ((tid & 63) == 0) { red[wave * 2] = s1; red[wave * 2 + 1] = s2; }
  __syncthreads();
  s1 = red[0] + red[2] + red[4] + red[6];
  s2 = red[1] + red[3] + red[5] + red[7];
  const float mean = s1 * (1.0f / 1024.0f);
  const float var = s2 * (1.0f / 1024.0f) - mean * mean;
  const float inv = rsqrtf(var + 1e-5f);
  const float4 gv = reinterpret_cast<const float4*>(g)[tid];
  const float4 bv = reinterpret_cast<const float4*>(b)[tid];
  union { bf16 h[4]; uint2 u; } pk;
#pragma unroll
  for (int j = 0; j < 4; j++) {
    float gj = (&gv.x)[j], bj = (&bv.x)[j];
    pk.h[j] = __float2bfloat16((v[j] - mean) * inv * gj + bj);
  }
  reinterpret_cast<uint2*>(out + (size_t)row * 1024)[tid] = pk.u;
}

// ---------------------------------------------------------------- GEMM: C[M,N] = A[M,K](bf16) * Wt[N,K](bf16)^T + epilogue
template <int EPI>
__global__ __launch_bounds__(256) void gemm_bt(
    const bf16* __restrict__ A, const bf16* __restrict__ W,
    const float* __restrict__ bias, const void* __restrict__ resid,
    void* __restrict__ Cout, int N, int K) {
  __shared__ __align__(16) bf16 As[128 * 64];
  __shared__ __align__(16) bf16 Bs[128 * 64];
  const int tid = threadIdx.x;
  const int wave = tid >> 6, lane = tid & 63;
  const int row0 = blockIdx.y << 7, col0 = blockIdx.x << 7;
  const int wr = (wave >> 1) << 6, wc = (wave & 1) << 6;
  const bf16* Ag = A + (size_t)row0 * K;
  const bf16* Bg = W + (size_t)col0 * K;

  f32x4 acc[4][4];
#pragma unroll
  for (int m = 0; m < 4; m++)
#pragma unroll
    for (int n = 0; n < 4; n++) acc[m][n] = (f32x4){0.f, 0.f, 0.f, 0.f};

  const int lr = lane >> 3, lc = (lane & 7) << 3;
  auto stage = [&](int kt) {
    const bf16* ag = Ag + (kt << 6);
    const bf16* bg = Bg + (kt << 6);
#pragma unroll
    for (int i = 0; i < 4; i++) {
      int br = (i << 5) + (wave << 3);
      gload_lds16(ag + (size_t)(br + lr) * K + lc, As + br * 64);
      gload_lds16(bg + (size_t)(br + lr) * K + lc, Bs + br * 64);
    }
  };
  stage(0);
  const int nk = K >> 6;
  for (int kt = 0; kt < nk; kt++) {
    __syncthreads();
#pragma unroll
    for (int kk = 0; kk < 2; kk++) {
      bf16x8 af[4], bfr[4];
      const int ko = (kk << 5) + ((lane >> 4) << 3);
#pragma unroll
      for (int m = 0; m < 4; m++)
        af[m] = *reinterpret_cast<const bf16x8*>(As + (wr + (m << 4) + (lane & 15)) * 64 + ko);
#pragma unroll
      for (int n = 0; n < 4; n++)
        bfr[n] = *reinterpret_cast<const bf16x8*>(Bs + (wc + (n << 4) + (lane & 15)) * 64 + ko);
#pragma unroll
      for (int m = 0; m < 4; m++)
#pragma unroll
        for (int n = 0; n < 4; n++)
          acc[m][n] = __builtin_amdgcn_mfma_f32_16x16x32_bf16(af[m], bfr[n], acc[m][n], 0, 0, 0);
    }
    __syncthreads();
    if (kt + 1 < nk) stage(kt + 1);
  }
  const int rbase = row0 + wr + ((lane >> 4) << 2);
  const int cbase = col0 + wc + (lane & 15);
#pragma unroll
  for (int m = 0; m < 4; m++) {
#pragma unroll
    for (int n = 0; n < 4; n++) {
      const int col = cbase + (n << 4);
      const float bv = bias[col];
#pragma unroll
      for (int j = 0; j < 4; j++) {
        const int row = rbase + (m << 4) + j;
        float v = acc[m][n][j] + bv;
        if constexpr (EPI == 0) {
          int part = col >> 10, rem = col & 1023;
          int hh = rem >> 6, hd = rem & 63;
          int b = row >> 11, sq = row & 2047;
          ((bf16*)Cout)[(size_t)part * 8388608 +
                        ((size_t)((b << 4) + hh) * 2048 + sq) * 64 + hd] =
              __float2bfloat16(v);
        } else if constexpr (EPI == 1) {
          v += ((const float*)resid)[(size_t)row * N + col];
          ((bf16*)Cout)[(size_t)row * N + col] = __float2bfloat16(v);
        } else if constexpr (EPI == 2) {
          ((bf16*)Cout)[(size_t)row * N + col] = __float2bfloat16(gelu_new(v));
        } else {
          v += bf16bits_to_f32(((const unsigned short*)resid)[(size_t)row * N + col]);
          ((float*)Cout)[(size_t)row * N + col] = v;
        }
      }
    }
  }
}

// ---------------------------------------------------------------- flash attention, causal, S=2048 HD=64
// Round-6 structure verbatim (pairing {p,15-p}, reg-staged, stride-64 LDS,
// Ps[128][72]) with ONE change: V staged linearly from pre-transposed Vt
// (global [bh][hd][s]) instead of the 16-way-conflict in-LDS scatter.
__global__ __launch_bounds__(256) void attn_k(
    const bf16* __restrict__ Qb, const bf16* __restrict__ Kb,
    const bf16* __restrict__ Vtg, const float* __restrict__ amask,
    bf16* __restrict__ Aout) {
  __shared__ __align__(16) bf16 Ks[64 * 64];
  __shared__ __align__(16) bf16 Vt[64 * 64];   // [hd][kv]
  __shared__ __align__(16) bf16 Ps[128][72];
  const int tid = threadIdx.x, wave = tid >> 6, lane = tid & 63;
  const int p = blockIdx.x, bh = blockIdx.y;
  const int b = bh >> 4, h = bh & 15;
  const size_t base = (size_t)bh * 131072;
  const bf16* Kg0 = Kb + base;
  const bf16* Vg0 = Vtg + base;

  for (int ph = 0; ph < 2; ph++) {
    const int qt = ph ? (15 - p) : p;
    const int q0 = qt << 7;

    bf16x8 qf[2][2];
    const int qrow = q0 + (wave << 5) + (lane & 15);
#pragma unroll
    for (int m = 0; m < 2; m++)
#pragma unroll
      for (int kk = 0; kk < 2; kk++)
        qf[m][kk] = *reinterpret_cast<const bf16x8*>(
            Qb + base + (size_t)(qrow + (m << 4)) * 64 + (kk << 5) + ((lane >> 4) << 3));

    f32x4 oacc[2][4];
    float mst[2][4], lst[2][4];
#pragma unroll
    for (int m = 0; m < 2; m++) {
#pragma unroll
      for (int n = 0; n < 4; n++) oacc[m][n] = (f32x4){0.f, 0.f, 0.f, 0.f};
#pragma unroll
      for (int j = 0; j < 4; j++) { mst[m][j] = -INFINITY; lst[m][j] = 0.f; }
    }

    const int ktmax = (q0 + 127) >> 6;  // inclusive
    for (int kt = 0; kt <= ktmax; kt++) {
      const bf16* Kg = Kg0 + (kt << 12);
      const bf16* Vg = Vg0 + (kt << 6);
      bf16x8 rk[2], rv[2];
#pragma unroll
      for (int i = 0; i < 2; i++) {
        const int ci = (i << 8) + tid;
        const int r = ci >> 3, cb = (ci & 7) << 3;
        rk[i] = *reinterpret_cast<const bf16x8*>(Kg + r * 64 + cb);            // K[kv=r][hd]
        rv[i] = *reinterpret_cast<const bf16x8*>(Vg + (size_t)r * 2048 + cb);  // Vt[hd=r][kv]
      }
      __syncthreads();  // prev iter/phase LDS reads done
#pragma unroll
      for (int i = 0; i < 2; i++) {
        const int ci = (i << 8) + tid;
        const int r = ci >> 3, cb = (ci & 7) << 3;
        *reinterpret_cast<bf16x8*>(Ks + r * 64 + cb) = rk[i];
        *reinterpret_cast<bf16x8*>(Vt + r * 64 + cb) = rv[i];
      }
      __syncthreads();

      f32x4 s[2][4];
#pragma unroll
      for (int m = 0; m < 2; m++)
#pragma unroll
        for (int n = 0; n < 4; n++) s[m][n] = (f32x4){0.f, 0.f, 0.f, 0.f};
#pragma unroll
      for (int kk = 0; kk < 2; kk++) {
        bf16x8 kf[4];
        const int ko = (kk << 5) + ((lane >> 4) << 3);
#pragma unroll
        for (int n = 0; n < 4; n++)
          kf[n] = *reinterpret_cast<const bf16x8*>(Ks + ((n << 4) + (lane & 15)) * 64 + ko);
#pragma unroll
        for (int m = 0; m < 2; m++)
#pragma unroll
          for (int n = 0; n < 4; n++)
            s[m][n] = __builtin_amdgcn_mfma_f32_16x16x32_bf16(qf[m][kk], kf[n], s[m][n], 0, 0, 0);
      }
      float am[4];
#pragma unroll
      for (int n = 0; n < 4; n++)
        am[n] = amask[b * 2048 + (kt << 6) + (n << 4) + (lane & 15)];
      const int rq = q0 + (wave << 5) + ((lane >> 4) << 2);
#pragma unroll
      for (int m = 0; m < 2; m++)
#pragma unroll
        for (int n = 0; n < 4; n++)
#pragma unroll
          for (int j = 0; j < 4; j++) {
            int r = rq + (m << 4) + j;
            int c = (kt << 6) + (n << 4) + (lane & 15);
            float v = s[m][n][j] * 0.125f + am[n];
            if (c > r) v = -1e30f;
            s[m][n][j] = v;
          }
#pragma unroll
      for (int m = 0; m < 2; m++) {
#pragma unroll
        for (int j = 0; j < 4; j++) {
          float rm = -INFINITY;
#pragma unroll
          for (int n = 0; n < 4; n++) rm = fmaxf(rm, s[m][n][j]);
#pragma unroll
          for (int off = 1; off < 16; off <<= 1) rm = fmaxf(rm, __shfl_xor(rm, off));
          float mnew = fmaxf(mst[m][j], rm);
          float fac = __expf(mst[m][j] - mnew);
          float rs = 0.f;
#pragma unroll
          for (int n = 0; n < 4; n++) {
            float pv = __expf(s[m][n][j] - mnew);
            s[m][n][j] = pv;
            rs += pv;
          }
#pragma unroll
          for (int off = 1; off < 16; off <<= 1) rs += __shfl_xor(rs, off);
          lst[m][j] = lst[m][j] * fac + rs;
          mst[m][j] = mnew;
#pragma unroll
          for (int n = 0; n < 4; n++) oacc[m][n][j] *= fac;
        }
      }
#pragma unroll
      for (int m = 0; m < 2; m++)
#pragma unroll
        for (int n = 0; n < 4; n++)
#pragma unroll
          for (int j = 0; j < 4; j++)
            Ps[(wave << 5) + (m << 4) + ((lane >> 4) << 2) + j][(n << 4) + (lane & 15)] =
                __float2bfloat16(s[m][n][j]);
      __syncthreads();
#pragma unroll
      for (int kk = 0; kk < 2; kk++) {
        bf16x8 pa[2], vb[4];
        const int ko = (kk << 5) + ((lane >> 4) << 3);
#pragma unroll
        for (int m = 0; m < 2; m++)
          pa[m] = *reinterpret_cast<const bf16x8*>(&Ps[(wave << 5) + (m << 4) + (lane & 15)][ko]);
#pragma unroll
        for (int n = 0; n < 4; n++)
          vb[n] = *reinterpret_cast<const bf16x8*>(Vt + ((n << 4) + (lane & 15)) * 64 + ko);
#pragma unroll
        for (int m = 0; m < 2; m++)
#pragma unroll
          for (int n = 0; n < 4; n++)
            oacc[m][n] = __builtin_amdgcn_mfma_f32_16x16x32_bf16(pa[m], vb[n], oacc[m][n], 0, 0, 0);
      }
    }
#pragma unroll
    for (int m = 0; m < 2; m++)
#pragma unroll
      for (int n = 0; n < 4; n++)
#pragma unroll
        for (int j = 0; j < 4; j++) {
          int r = q0 + (wave << 5) + (m << 4) + ((lane >> 4) << 2) + j;
          int c = (h << 6) + (n << 4) + (lane & 15);
          float v = oacc[m][n][j] / lst[m][j];
          Aout[((size_t)(b * 2048 + r)) * 1024 + c] = __float2bfloat16(v);
        }
  }
}

// ---------------------------------------------------------------- launch
extern "C" void kernel_launch(void* const* d_in, const int* in_sizes, int n_in,
                              void* d_out, int out_size, void* d_ws, size_t ws_size,
                              hipStream_t stream) {
  const float* hid   = (const float*)d_in[0];
  const float* amask = (const float*)d_in[1];
  const float* ln1g  = (const float*)d_in[2];
  const float* ln1b  = (const float*)d_in[3];
  const float* Wa    = (const float*)d_in[4];
  const float* ba    = (const float*)d_in[5];
  const float* Wp    = (const float*)d_in[6];
  const float* bp    = (const float*)d_in[7];
  const float* ln2g  = (const float*)d_in[8];
  const float* ln2b  = (const float*)d_in[9];
  const float* Wf    = (const float*)d_in[10];
  const float* bfc   = (const float*)d_in[11];
  const float* Wf2   = (const float*)d_in[12];
  const float* bf2   = (const float*)d_in[13];
  float* out = (float*)d_out;   // reference output dtype is FLOAT32

  if (ws_size < 125829120u) return;  // 120 MB layout (proven to fit)
  char* ws = (char*)d_ws;
  bf16* WtA  = (bf16*)(ws + 0);          //  6 MB
  bf16* WtP  = (bf16*)(ws + 6291456);    //  2 MB
  bf16* WtF  = (bf16*)(ws + 8388608);    //  8 MB
  bf16* WtF2 = (bf16*)(ws + 16777216);   //  8 MB
  bf16* h    = (bf16*)(ws + 25165824);   // 16 MB (reused as h2)
  bf16* qkv  = (bf16*)(ws + 41943040);   // 48 MB
  bf16* a    = (bf16*)(ws + 92274688);   // 16 MB
  bf16* Vt   = (bf16*)(ws + 109051904);  // 16 MB (dead after attn; reused as xmid)
  bf16* xmid = (bf16*)(ws + 109051904);  // 16 MB -> total 120 MB
  bf16* h2  = h;
  bf16* fc1 = qkv;  // overlays qkv+a (both dead): 64 MB

  dim3 blk(256);
  transpose_cvt<<<dim3(48, 16), blk, 0, stream>>>(Wa, WtA, 1024, 3072);
  transpose_cvt<<<dim3(16, 16), blk, 0, stream>>>(Wp, WtP, 1024, 1024);
  transpose_cvt<<<dim3(64, 16), blk, 0, stream>>>(Wf, WtF, 1024, 4096);
  transpose_cvt<<<dim3(16, 64), blk, 0, stream>>>(Wf2, WtF2, 4096, 1024);

  ln_f32in<<<8192, blk, 0, stream>>>(hid, ln1g, ln1b, h);
  gemm_bt<0><<<dim3(24, 64), blk, 0, stream>>>(h, WtA, ba, nullptr, qkv, 3072, 1024);
  vt_k<<<dim3(32, 64), blk, 0, stream>>>(qkv + 16777216, Vt);
  attn_k<<<dim3(8, 64), blk, 0, stream>>>(qkv, qkv + 8388608, Vt, amask, a);
  gemm_bt<1><<<dim3(8, 64), blk, 0, stream>>>(a, WtP, bp, hid, xmid, 1024, 1024);
  ln_bf16in<<<8192, blk, 0, stream>>>(xmid, ln2g, ln2b, h2);
  gemm_bt<2><<<dim3(32, 64), blk, 0, stream>>>(h2, WtF, bfc, nullptr, fc1, 4096, 1024);
  gemm_bt<3><<<dim3(8, 64), blk, 0, stream>>>(fc1, WtF2, bf2, xmid, out, 1024, 4096);
}

// Round 9
// 478.942 us; speedup vs baseline: 1.3492x; 1.0691x over previous
//
#include <hip/hip_runtime.h>
#include <hip/hip_bf16.h>

typedef __hip_bfloat16 bf16;
typedef __attribute__((ext_vector_type(8))) short bf16x8;
typedef __attribute__((ext_vector_type(4))) float f32x4;

__device__ __forceinline__ void gload_lds16(const void* g, void* s) {
  __builtin_amdgcn_global_load_lds(
      (__attribute__((address_space(1))) void*)(unsigned long long)(uintptr_t)g,
      (__attribute__((address_space(3))) void*)(unsigned int)(uintptr_t)s,
      16, 0, 0);
}

__device__ __forceinline__ float gelu_new(float x) {
  float x3 = x * x * x;
  return 0.5f * x * (1.0f + tanhf(0.7978845608028654f * (x + 0.044715f * x3)));
}

__device__ __forceinline__ float bf16bits_to_f32(unsigned short u) {
  return __uint_as_float(((unsigned)u) << 16);
}

// ---------------------------------------------------------------- weight transpose+cast: W[K][N] f32 -> Wt[N][K] bf16
__global__ __launch_bounds__(256) void transpose_cvt(
    const float* __restrict__ W, bf16* __restrict__ Wt, int K, int N) {
  __shared__ float t[64][65];
  const int k0 = blockIdx.y << 6, n0 = blockIdx.x << 6;
  const int tid = threadIdx.x;
#pragma unroll
  for (int i = 0; i < 16; i++) {
    int idx = (i << 8) + tid;
    int r = idx >> 6, c = idx & 63;
    t[r][c] = W[(size_t)(k0 + r) * N + n0 + c];
  }
  __syncthreads();
#pragma unroll
  for (int i = 0; i < 16; i++) {
    int idx = (i << 8) + tid;
    int r = idx >> 6, c = idx & 63;
    Wt[(size_t)(n0 + r) * K + k0 + c] = __float2bfloat16(t[c][r]);
  }
}

// ---------------------------------------------------------------- V transpose: V[bh][s][64] -> Vt[bh][64][s]  (bit-exact)
__global__ __launch_bounds__(256) void vt_k(
    const bf16* __restrict__ V, bf16* __restrict__ Vt) {
  __shared__ __align__(16) short t[64][72];
  const int tid = threadIdx.x;
  const int st = blockIdx.x, bh = blockIdx.y;
  const short* src = (const short*)(V + (size_t)bh * 131072 + (size_t)st * 4096);
#pragma unroll
  for (int i = 0; i < 2; i++) {
    int idx = (i << 8) + tid;
    int r = idx >> 3, c0 = (idx & 7) << 3;
    *reinterpret_cast<bf16x8*>(&t[r][c0]) =
        *reinterpret_cast<const bf16x8*>(src + r * 64 + c0);
  }
  __syncthreads();
  short* dst = (short*)(Vt + (size_t)bh * 131072 + (size_t)st * 64);
#pragma unroll
  for (int i = 0; i < 2; i++) {
    int idx = (i << 8) + tid;
    int hd = idx >> 3, s0 = (idx & 7) << 3;
    bf16x8 o;
#pragma unroll
    for (int j = 0; j < 8; j++) o[j] = t[s0 + j][hd];  // short = short: bit copy
    *reinterpret_cast<bf16x8*>(dst + (size_t)hd * 2048 + s0) = o;
  }
}

// ---------------------------------------------------------------- layernorm, f32 input -> bf16 out (D=1024, block=256)
__global__ __launch_bounds__(256) void ln_f32in(
    const float* __restrict__ x, const float* __restrict__ g,
    const float* __restrict__ b, bf16* __restrict__ out) {
  const int row = blockIdx.x, tid = threadIdx.x;
  const float4 v = reinterpret_cast<const float4*>(x + (size_t)row * 1024)[tid];
  float s1 = v.x + v.y + v.z + v.w;
  float s2 = v.x * v.x + v.y * v.y + v.z * v.z + v.w * v.w;
#pragma unroll
  for (int off = 32; off >= 1; off >>= 1) {
    s1 += __shfl_xor(s1, off);
    s2 += __shfl_xor(s2, off);
  }
  __shared__ float red[8];
  const int wave = tid >> 6;
  if ((tid & 63) == 0) { red[wave * 2] = s1; red[wave * 2 + 1] = s2; }
  __syncthreads();
  s1 = red[0] + red[2] + red[4] + red[6];
  s2 = red[1] + red[3] + red[5] + red[7];
  const float mean = s1 * (1.0f / 1024.0f);
  const float var = s2 * (1.0f / 1024.0f) - mean * mean;
  const float inv = rsqrtf(var + 1e-5f);
  const float4 gv = reinterpret_cast<const float4*>(g)[tid];
  const float4 bv = reinterpret_cast<const float4*>(b)[tid];
  union { bf16 h[4]; uint2 u; } pk;
  pk.h[0] = __float2bfloat16((v.x - mean) * inv * gv.x + bv.x);
  pk.h[1] = __float2bfloat16((v.y - mean) * inv * gv.y + bv.y);
  pk.h[2] = __float2bfloat16((v.z - mean) * inv * gv.z + bv.z);
  pk.h[3] = __float2bfloat16((v.w - mean) * inv * gv.w + bv.w);
  reinterpret_cast<uint2*>(out + (size_t)row * 1024)[tid] = pk.u;
}

// ---------------------------------------------------------------- layernorm, bf16 input -> bf16 out
__global__ __launch_bounds__(256) void ln_bf16in(
    const bf16* __restrict__ x, const float* __restrict__ g,
    const float* __restrict__ b, bf16* __restrict__ out) {
  const int row = blockIdx.x, tid = threadIdx.x;
  union { uint2 u; unsigned short h[4]; } raw;
  raw.u = reinterpret_cast<const uint2*>(x + (size_t)row * 1024)[tid];
  float v[4];
#pragma unroll
  for (int j = 0; j < 4; j++) v[j] = bf16bits_to_f32(raw.h[j]);
  float s1 = v[0] + v[1] + v[2] + v[3];
  float s2 = v[0] * v[0] + v[1] * v[1] + v[2] * v[2] + v[3] * v[3];
#pragma unroll
  for (int off = 32; off >= 1; off >>= 1) {
    s1 += __shfl_xor(s1, off);
    s2 += __shfl_xor(s2, off);
  }
  __shared__ float red[8];
  const int wave = tid >> 6;
  if ((tid & 63) == 0) { red[wave * 2] = s1; red[wave * 2 + 1] = s2; }
  __syncthreads();
  s1 = red[0] + red[2] + red[4] + red[6];
  s2 = red[1] + red[3] + red[5] + red[7];
  const float mean = s1 * (1.0f / 1024.0f);
  const float var = s2 * (1.0f / 1024.0f) - mean * mean;
  const float inv = rsqrtf(var + 1e-5f);
  const float4 gv = reinterpret_cast<const float4*>(g)[tid];
  const float4 bv = reinterpret_cast<const float4*>(b)[tid];
  union { bf16 h[4]; uint2 u; } pk;
#pragma unroll
  for (int j = 0; j < 4; j++) {
    float gj = (&gv.x)[j], bj = (&bv.x)[j];
    pk.h[j] = __float2bfloat16((v[j] - mean) * inv * gj + bj);
  }
  reinterpret_cast<uint2*>(out + (size_t)row * 1024)[tid] = pk.u;
}

// ---------------------------------------------------------------- GEMM: C[M,N] = A[M,K](bf16) * Wt[N,K](bf16)^T + epilogue
// 2-phase pipelined: double-buffered LDS, stage(kt+1) issued BEFORE compute(kt),
// ONE barrier per K-step (barrier drains vmcnt -> staged tile visible, and
// guarantees all reads of the buffer being overwritten completed).
template <int EPI>
__global__ __launch_bounds__(256) void gemm_bt(
    const bf16* __restrict__ A, const bf16* __restrict__ W,
    const float* __restrict__ bias, const void* __restrict__ resid,
    void* __restrict__ Cout, int N, int K) {
  __shared__ __align__(16) bf16 As[2][128 * 64];
  __shared__ __align__(16) bf16 Bs[2][128 * 64];
  const int tid = threadIdx.x;
  const int wave = tid >> 6, lane = tid & 63;
  const int row0 = blockIdx.y << 7, col0 = blockIdx.x << 7;
  const int wr = (wave >> 1) << 6, wc = (wave & 1) << 6;
  const bf16* Ag = A + (size_t)row0 * K;
  const bf16* Bg = W + (size_t)col0 * K;

  f32x4 acc[4][4];
#pragma unroll
  for (int m = 0; m < 4; m++)
#pragma unroll
    for (int n = 0; n < 4; n++) acc[m][n] = (f32x4){0.f, 0.f, 0.f, 0.f};

  const int lr = lane >> 3, lc = (lane & 7) << 3;
  auto stage = [&](int kt, int buf) {
    const bf16* ag = Ag + (kt << 6);
    const bf16* bg = Bg + (kt << 6);
#pragma unroll
    for (int i = 0; i < 4; i++) {
      int br = (i << 5) + (wave << 3);
      gload_lds16(ag + (size_t)(br + lr) * K + lc, As[buf] + br * 64);
      gload_lds16(bg + (size_t)(br + lr) * K + lc, Bs[buf] + br * 64);
    }
  };
  stage(0, 0);
  const int nk = K >> 6;
  int cur = 0;
  for (int kt = 0; kt < nk; kt++) {
    __syncthreads();   // drains stage(kt) into cur; protects cur^1 overwrite
    if (kt + 1 < nk) stage(kt + 1, cur ^ 1);   // loads fly during compute
    const bf16* Asc = As[cur];
    const bf16* Bsc = Bs[cur];
#pragma unroll
    for (int kk = 0; kk < 2; kk++) {
      bf16x8 af[4], bfr[4];
      const int ko = (kk << 5) + ((lane >> 4) << 3);
#pragma unroll
      for (int m = 0; m < 4; m++)
        af[m] = *reinterpret_cast<const bf16x8*>(Asc + (wr + (m << 4) + (lane & 15)) * 64 + ko);
#pragma unroll
      for (int n = 0; n < 4; n++)
        bfr[n] = *reinterpret_cast<const bf16x8*>(Bsc + (wc + (n << 4) + (lane & 15)) * 64 + ko);
#pragma unroll
      for (int m = 0; m < 4; m++)
#pragma unroll
        for (int n = 0; n < 4; n++)
          acc[m][n] = __builtin_amdgcn_mfma_f32_16x16x32_bf16(af[m], bfr[n], acc[m][n], 0, 0, 0);
    }
    cur ^= 1;
  }
  const int rbase = row0 + wr + ((lane >> 4) << 2);
  const int cbase = col0 + wc + (lane & 15);
#pragma unroll
  for (int m = 0; m < 4; m++) {
#pragma unroll
    for (int n = 0; n < 4; n++) {
      const int col = cbase + (n << 4);
      const float bv = bias[col];
#pragma unroll
      for (int j = 0; j < 4; j++) {
        const int row = rbase + (m << 4) + j;
        float v = acc[m][n][j] + bv;
        if constexpr (EPI == 0) {
          int part = col >> 10, rem = col & 1023;
          int hh = rem >> 6, hd = rem & 63;
          int b = row >> 11, sq = row & 2047;
          ((bf16*)Cout)[(size_t)part * 8388608 +
                        ((size_t)((b << 4) + hh) * 2048 + sq) * 64 + hd] =
              __float2bfloat16(v);
        } else if constexpr (EPI == 1) {
          v += ((const float*)resid)[(size_t)row * N + col];
          ((bf16*)Cout)[(size_t)row * N + col] = __float2bfloat16(v);
        } else if constexpr (EPI == 2) {
          ((bf16*)Cout)[(size_t)row * N + col] = __float2bfloat16(gelu_new(v));
        } else {
          v += bf16bits_to_f32(((const unsigned short*)resid)[(size_t)row * N + col]);
          ((float*)Cout)[(size_t)row * N + col] = v;
        }
      }
    }
  }
}

// ---------------------------------------------------------------- flash attention, causal, S=2048 HD=64
// (round-8 passing version, unchanged)
__global__ __launch_bounds__(256) void attn_k(
    const bf16* __restrict__ Qb, const bf16* __restrict__ Kb,
    const bf16* __restrict__ Vtg, const float* __restrict__ amask,
    bf16* __restrict__ Aout) {
  __shared__ __align__(16) bf16 Ks[64 * 64];
  __shared__ __align__(16) bf16 Vt[64 * 64];   // [hd][kv]
  __shared__ __align__(16) bf16 Ps[128][72];
  const int tid = threadIdx.x, wave = tid >> 6, lane = tid & 63;
  const int p = blockIdx.x, bh = blockIdx.y;
  const int b = bh >> 4, h = bh & 15;
  const size_t base = (size_t)bh * 131072;
  const bf16* Kg0 = Kb + base;
  const bf16* Vg0 = Vtg + base;

  for (int ph = 0; ph < 2; ph++) {
    const int qt = ph ? (15 - p) : p;
    const int q0 = qt << 7;

    bf16x8 qf[2][2];
    const int qrow = q0 + (wave << 5) + (lane & 15);
#pragma unroll
    for (int m = 0; m < 2; m++)
#pragma unroll
      for (int kk = 0; kk < 2; kk++)
        qf[m][kk] = *reinterpret_cast<const bf16x8*>(
            Qb + base + (size_t)(qrow + (m << 4)) * 64 + (kk << 5) + ((lane >> 4) << 3));

    f32x4 oacc[2][4];
    float mst[2][4], lst[2][4];
#pragma unroll
    for (int m = 0; m < 2; m++) {
#pragma unroll
      for (int n = 0; n < 4; n++) oacc[m][n] = (f32x4){0.f, 0.f, 0.f, 0.f};
#pragma unroll
      for (int j = 0; j < 4; j++) { mst[m][j] = -INFINITY; lst[m][j] = 0.f; }
    }

    const int ktmax = (q0 + 127) >> 6;  // inclusive
    for (int kt = 0; kt <= ktmax; kt++) {
      const bf16* Kg = Kg0 + (kt << 12);
      const bf16* Vg = Vg0 + (kt << 6);
      bf16x8 rk[2], rv[2];
#pragma unroll
      for (int i = 0; i < 2; i++) {
        const int ci = (i << 8) + tid;
        const int r = ci >> 3, cb = (ci & 7) << 3;
        rk[i] = *reinterpret_cast<const bf16x8*>(Kg + r * 64 + cb);
        rv[i] = *reinterpret_cast<const bf16x8*>(Vg + (size_t)r * 2048 + cb);
      }
      __syncthreads();
#pragma unroll
      for (int i = 0; i < 2; i++) {
        const int ci = (i << 8) + tid;
        const int r = ci >> 3, cb = (ci & 7) << 3;
        *reinterpret_cast<bf16x8*>(Ks + r * 64 + cb) = rk[i];
        *reinterpret_cast<bf16x8*>(Vt + r * 64 + cb) = rv[i];
      }
      __syncthreads();

      f32x4 s[2][4];
#pragma unroll
      for (int m = 0; m < 2; m++)
#pragma unroll
        for (int n = 0; n < 4; n++) s[m][n] = (f32x4){0.f, 0.f, 0.f, 0.f};
#pragma unroll
      for (int kk = 0; kk < 2; kk++) {
        bf16x8 kf[4];
        const int ko = (kk << 5) + ((lane >> 4) << 3);
#pragma unroll
        for (int n = 0; n < 4; n++)
          kf[n] = *reinterpret_cast<const bf16x8*>(Ks + ((n << 4) + (lane & 15)) * 64 + ko);
#pragma unroll
        for (int m = 0; m < 2; m++)
#pragma unroll
          for (int n = 0; n < 4; n++)
            s[m][n] = __builtin_amdgcn_mfma_f32_16x16x32_bf16(qf[m][kk], kf[n], s[m][n], 0, 0, 0);
      }
      float am[4];
#pragma unroll
      for (int n = 0; n < 4; n++)
        am[n] = amask[b * 2048 + (kt << 6) + (n << 4) + (lane & 15)];
      const int rq = q0 + (wave << 5) + ((lane >> 4) << 2);
#pragma unroll
      for (int m = 0; m < 2; m++)
#pragma unroll
        for (int n = 0; n < 4; n++)
#pragma unroll
          for (int j = 0; j < 4; j++) {
            int r = rq + (m << 4) + j;
            int c = (kt << 6) + (n << 4) + (lane & 15);
            float v = s[m][n][j] * 0.125f + am[n];
            if (c > r) v = -1e30f;
            s[m][n][j] = v;
          }
#pragma unroll
      for (int m = 0; m < 2; m++) {
#pragma unroll
        for (int j = 0; j < 4; j++) {
          float rm = -INFINITY;
#pragma unroll
          for (int n = 0; n < 4; n++) rm = fmaxf(rm, s[m][n][j]);
#pragma unroll
          for (int off = 1; off < 16; off <<= 1) rm = fmaxf(rm, __shfl_xor(rm, off));
          float mnew = fmaxf(mst[m][j], rm);
          float fac = __expf(mst[m][j] - mnew);
          float rs = 0.f;
#pragma unroll
          for (int n = 0; n < 4; n++) {
            float pv = __expf(s[m][n][j] - mnew);
            s[m][n][j] = pv;
            rs += pv;
          }
#pragma unroll
          for (int off = 1; off < 16; off <<= 1) rs += __shfl_xor(rs, off);
          lst[m][j] = lst[m][j] * fac + rs;
          mst[m][j] = mnew;
#pragma unroll
          for (int n = 0; n < 4; n++) oacc[m][n][j] *= fac;
        }
      }
#pragma unroll
      for (int m = 0; m < 2; m++)
#pragma unroll
        for (int n = 0; n < 4; n++)
#pragma unroll
          for (int j = 0; j < 4; j++)
            Ps[(wave << 5) + (m << 4) + ((lane >> 4) << 2) + j][(n << 4) + (lane & 15)] =
                __float2bfloat16(s[m][n][j]);
      __syncthreads();
#pragma unroll
      for (int kk = 0; kk < 2; kk++) {
        bf16x8 pa[2], vb[4];
        const int ko = (kk << 5) + ((lane >> 4) << 3);
#pragma unroll
        for (int m = 0; m < 2; m++)
          pa[m] = *reinterpret_cast<const bf16x8*>(&Ps[(wave << 5) + (m << 4) + (lane & 15)][ko]);
#pragma unroll
        for (int n = 0; n < 4; n++)
          vb[n] = *reinterpret_cast<const bf16x8*>(Vt + ((n << 4) + (lane & 15)) * 64 + ko);
#pragma unroll
        for (int m = 0; m < 2; m++)
#pragma unroll
          for (int n = 0; n < 4; n++)
            oacc[m][n] = __builtin_amdgcn_mfma_f32_16x16x32_bf16(pa[m], vb[n], oacc[m][n], 0, 0, 0);
      }
    }
#pragma unroll
    for (int m = 0; m < 2; m++)
#pragma unroll
      for (int n = 0; n < 4; n++)
#pragma unroll
        for (int j = 0; j < 4; j++) {
          int r = q0 + (wave << 5) + (m << 4) + ((lane >> 4) << 2) + j;
          int c = (h << 6) + (n << 4) + (lane & 15);
          float v = oacc[m][n][j] / lst[m][j];
          Aout[((size_t)(b * 2048 + r)) * 1024 + c] = __float2bfloat16(v);
        }
  }
}

// ---------------------------------------------------------------- launch
extern "C" void kernel_launch(void* const* d_in, const int* in_sizes, int n_in,
                              void* d_out, int out_size, void* d_ws, size_t ws_size,
                              hipStream_t stream) {
  const float* hid   = (const float*)d_in[0];
  const float* amask = (const float*)d_in[1];
  const float* ln1g  = (const float*)d_in[2];
  const float* ln1b  = (const float*)d_in[3];
  const float* Wa    = (const float*)d_in[4];
  const float* ba    = (const float*)d_in[5];
  const float* Wp    = (const float*)d_in[6];
  const float* bp    = (const float*)d_in[7];
  const float* ln2g  = (const float*)d_in[8];
  const float* ln2b  = (const float*)d_in[9];
  const float* Wf    = (const float*)d_in[10];
  const float* bfc   = (const float*)d_in[11];
  const float* Wf2   = (const float*)d_in[12];
  const float* bf2   = (const float*)d_in[13];
  float* out = (float*)d_out;   // reference output dtype is FLOAT32

  if (ws_size < 125829120u) return;  // 120 MB layout (proven to fit)
  char* ws = (char*)d_ws;
  bf16* WtA  = (bf16*)(ws + 0);          //  6 MB
  bf16* WtP  = (bf16*)(ws + 6291456);    //  2 MB
  bf16* WtF  = (bf16*)(ws + 8388608);    //  8 MB
  bf16* WtF2 = (bf16*)(ws + 16777216);   //  8 MB
  bf16* h    = (bf16*)(ws + 25165824);   // 16 MB (reused as h2)
  bf16* qkv  = (bf16*)(ws + 41943040);   // 48 MB
  bf16* a    = (bf16*)(ws + 92274688);   // 16 MB
  bf16* Vt   = (bf16*)(ws + 109051904);  // 16 MB (dead after attn; reused as xmid)
  bf16* xmid = (bf16*)(ws + 109051904);  // 16 MB -> total 120 MB
  bf16* h2  = h;
  bf16* fc1 = qkv;  // overlays qkv+a (both dead): 64 MB

  dim3 blk(256);
  transpose_cvt<<<dim3(48, 16), blk, 0, stream>>>(Wa, WtA, 1024, 3072);
  transpose_cvt<<<dim3(16, 16), blk, 0, stream>>>(Wp, WtP, 1024, 1024);
  transpose_cvt<<<dim3(64, 16), blk, 0, stream>>>(Wf, WtF, 1024, 4096);
  transpose_cvt<<<dim3(16, 64), blk, 0, stream>>>(Wf2, WtF2, 4096, 1024);

  ln_f32in<<<8192, blk, 0, stream>>>(hid, ln1g, ln1b, h);
  gemm_bt<0><<<dim3(24, 64), blk, 0, stream>>>(h, WtA, ba, nullptr, qkv, 3072, 1024);
  vt_k<<<dim3(32, 64), blk, 0, stream>>>(qkv + 16777216, Vt);
  attn_k<<<dim3(8, 64), blk, 0, stream>>>(qkv, qkv + 8388608, Vt, amask, a);
  gemm_bt<1><<<dim3(8, 64), blk, 0, stream>>>(a, WtP, bp, hid, xmid, 1024, 1024);
  ln_bf16in<<<8192, blk, 0, stream>>>(xmid, ln2g, ln2b, h2);
  gemm_bt<2><<<dim3(32, 64), blk, 0, stream>>>(h2, WtF, bfc, nullptr, fc1, 4096, 1024);
  gemm_bt<3><<<dim3(8, 64), blk, 0, stream>>>(fc1, WtF2, bf2, xmid, out, 1024, 4096);
}